// Round 10
// baseline (135.560 us; speedup 1.0000x reference)
//
#include <hip/hip_runtime.h>

// Problem constants
#define B_  32
#define M_  64
#define K_  36
#define DS_ 512
#define DX_ 128
#define DQ_ 512
#define H_  256

// kern1 grid: s2 tiles of 8 rows, 8-way in-block split-K (512 threads)
#define S2B 512             // 256 tiles x 2 mats
#define PXB 288             // 1152/4 rows (round-9 form)
#define QPB 32

// ---------------------------------------------------------------------------
// kern1 (grid 832 x 512): all GEMMs + fused hs.
// s2 blocks: 8 waves = 8 K-chunks of 64 (split-K in the WAVE dim), lane l
// owns cols 4l..4l+3, rows live in the ACCUMULATOR (8 rows x 4 cols = 32
// acc/thread). Per k-quad: 4 float4 W loads + 8 LDS A-broadcasts feed 128
// FMAs (~91% FMA issue density vs round-9's 50%). Each W element is loaded
// exactly once per block (no round-8 duplication). 8-way combine through a
// 64 KB LDS buffer that unions with the A-stage (dead after the K loop).
//   blocks [0,512):    tile=bid>>1, mat=bid&1.
//     mat=0: pre_s[8 rows] = s2@w_s
//     mat=1: hs[8 rows] = relu(s2@h_w1 + h_b1) @ h_w2   (fused in-block)
//   blocks [512,800):  px[4 rows] = x0@w_x + score_b1   (K=128, round-9 form)
//   blocks [800,832):  qpre[b]    = q[b]@w_q            (K=512, round-9 form)
// ---------------------------------------------------------------------------
__global__ __launch_bounds__(512, 4) void kern1(
    const float* __restrict__ s2,        // (2048,512)
    const float* __restrict__ x0,        // (1152,128)
    const float* __restrict__ q,         // (32,512)
    const float* __restrict__ score_w1,  // (1152,256)
    const float* __restrict__ score_b1,  // (256)
    const float* __restrict__ h_w1,      // (512,256)
    const float* __restrict__ h_b1,      // (256)
    const float* __restrict__ h_w2,      // (256,128)
    float* __restrict__ pre_s,           // (2048,256)
    float* __restrict__ px,              // (1152,256)
    float* __restrict__ qpre,            // (32,256)
    float* __restrict__ hs)              // (2048,128)
{
    // 64 KB union: A-stage (8x512 = 16 KB) during K-loop,
    // then partials part[w][r][c] (8x8x256 = 64 KB) for the combine.
    __shared__ float lds[16384];
    __shared__ float hre[8 * H_];        // 8 KB relu'd h1 rows (mat=1 only)

    const int t   = threadIdx.x;
    const int bid = blockIdx.x;
    const int l   = t & 63;
    const int w   = __builtin_amdgcn_readfirstlane(t >> 6);  // wave id 0..7

    if (bid < S2B) {                     // ---- s2 GEMMs ----
        const int tile = bid >> 1, mat = bid & 1;
        const float* Wm = mat ? h_w1 : score_w1;             // (512,256)

        {   // stage 8 rows of s2 (16 KB), two float4 per thread, coalesced
            const float* Asrc = s2 + (size_t)tile * 8 * DS_;
            *(float4*)&lds[t * 4]        = *(const float4*)(Asrc + t * 4);
            *(float4*)&lds[t * 4 + 2048] = *(const float4*)(Asrc + t * 4 + 2048);
        }
        __syncthreads();

        const float4* Wq = (const float4*)Wm + l;  // col-quad 4l, row stride 64
        const int k0 = w * 64;                     // this wave's K-chunk

        float4 acc[8];
        #pragma unroll
        for (int r = 0; r < 8; ++r) acc[r] = make_float4(0.f, 0.f, 0.f, 0.f);

        #pragma unroll 2
        for (int kq = 0; kq < 16; ++kq) {
            const int k = k0 + kq * 4;
            const float4 w0  = Wq[(size_t)(k + 0) * 64];
            const float4 w1  = Wq[(size_t)(k + 1) * 64];
            const float4 w2v = Wq[(size_t)(k + 2) * 64];
            const float4 w3  = Wq[(size_t)(k + 3) * 64];
            #pragma unroll
            for (int r = 0; r < 8; ++r) {
                const float4 a = *(const float4*)&lds[r * DS_ + k];  // broadcast
                acc[r].x = fmaf(a.x, w0.x, acc[r].x);
                acc[r].y = fmaf(a.x, w0.y, acc[r].y);
                acc[r].z = fmaf(a.x, w0.z, acc[r].z);
                acc[r].w = fmaf(a.x, w0.w, acc[r].w);
                acc[r].x = fmaf(a.y, w1.x, acc[r].x);
                acc[r].y = fmaf(a.y, w1.y, acc[r].y);
                acc[r].z = fmaf(a.y, w1.z, acc[r].z);
                acc[r].w = fmaf(a.y, w1.w, acc[r].w);
                acc[r].x = fmaf(a.z, w2v.x, acc[r].x);
                acc[r].y = fmaf(a.z, w2v.y, acc[r].y);
                acc[r].z = fmaf(a.z, w2v.z, acc[r].z);
                acc[r].w = fmaf(a.z, w2v.w, acc[r].w);
                acc[r].x = fmaf(a.w, w3.x, acc[r].x);
                acc[r].y = fmaf(a.w, w3.y, acc[r].y);
                acc[r].z = fmaf(a.w, w3.z, acc[r].z);
                acc[r].w = fmaf(a.w, w3.w, acc[r].w);
            }
        }
        __syncthreads();                 // all waves done reading A-stage

        #pragma unroll
        for (int r = 0; r < 8; ++r)      // part[w][r][4l..4l+3]
            *(float4*)&lds[w * 2048 + r * 256 + l * 4] = acc[r];
        __syncthreads();

        // final: this thread owns row rr=w, cols 4l..4l+3
        float4 s = *(const float4*)&lds[w * 256 + l * 4];
        #pragma unroll
        for (int ww = 1; ww < 8; ++ww) {
            const float4 p = *(const float4*)&lds[ww * 2048 + w * 256 + l * 4];
            s.x += p.x; s.y += p.y; s.z += p.z; s.w += p.w;
        }

        if (!mat) {                      // pre_s: coalesced float4 store
            *(float4*)(pre_s + ((size_t)tile * 8 + w) * H_ + l * 4) = s;
        } else {                         // fused hs = relu(h1+b1) @ h_w2
            const float4 bv = *(const float4*)(h_b1 + l * 4);
            float4 o;
            o.x = fmaxf(s.x + bv.x, 0.f);
            o.y = fmaxf(s.y + bv.y, 0.f);
            o.z = fmaxf(s.z + bv.z, 0.f);
            o.w = fmaxf(s.w + bv.w, 0.f);
            *(float4*)&hre[w * H_ + l * 4] = o;
            __syncthreads();

            const int row = w;           // 0..7
            const int f0  = l * 2;       // 2 output cols per lane
            const float* w2p = h_w2 + f0;
            float s0 = 0.f, s1 = 0.f;
            #pragma unroll 2
            for (int k = 0; k < H_; k += 4) {
                const float4 hv = *(const float4*)&hre[row * H_ + k];
                const float2 wa = *(const float2*)(w2p + (size_t)(k + 0) * DX_);
                const float2 wb = *(const float2*)(w2p + (size_t)(k + 1) * DX_);
                const float2 wc = *(const float2*)(w2p + (size_t)(k + 2) * DX_);
                const float2 wd = *(const float2*)(w2p + (size_t)(k + 3) * DX_);
                s0 = fmaf(hv.x, wa.x, s0); s1 = fmaf(hv.x, wa.y, s1);
                s0 = fmaf(hv.y, wb.x, s0); s1 = fmaf(hv.y, wb.y, s1);
                s0 = fmaf(hv.z, wc.x, s0); s1 = fmaf(hv.z, wc.y, s1);
                s0 = fmaf(hv.w, wd.x, s0); s1 = fmaf(hv.w, wd.y, s1);
            }
            *(float2*)(hs + ((size_t)tile * 8 + row) * DX_ + f0) =
                make_float2(s0, s1);
        }

    } else if (bid < S2B + PXB) {        // ---- px blocks (K=128) ----
        const int tile = bid - S2B;
        const int h    = t & 255;
        const int kh   = __builtin_amdgcn_readfirstlane(t >> 8);
        float* comb = &lds[4096];

        if (t < 128) {                   // stage 4 rows of x0 (2 KB)
            const float* Asrc = x0 + (size_t)tile * 4 * DX_;
            *(float4*)&lds[t * 4] = *(const float4*)(Asrc + t * 4);
        }
        __syncthreads();

        const float* Wp = score_w1 + (size_t)(DS_ + kh * 64) * H_ + h;
        const int ab = kh * 64;

        float acc[4];
        #pragma unroll
        for (int r = 0; r < 4; ++r) acc[r] = 0.f;

        #pragma unroll 4
        for (int k = 0; k < 64; k += 4) {
            const float b0 = Wp[(size_t)(k + 0) * H_];
            const float b1 = Wp[(size_t)(k + 1) * H_];
            const float b2 = Wp[(size_t)(k + 2) * H_];
            const float b3 = Wp[(size_t)(k + 3) * H_];
            #pragma unroll
            for (int r = 0; r < 4; ++r) {
                const float4 a = *(const float4*)&lds[r * DX_ + ab + k];
                acc[r] = fmaf(a.x, b0, acc[r]);
                acc[r] = fmaf(a.y, b1, acc[r]);
                acc[r] = fmaf(a.z, b2, acc[r]);
                acc[r] = fmaf(a.w, b3, acc[r]);
            }
        }
        if (kh) {
            #pragma unroll
            for (int r = 0; r < 4; ++r) comb[r * H_ + h] = acc[r];
        }
        __syncthreads();
        if (!kh) {
            const float b1v = score_b1[h];
            float* dst = px + (size_t)tile * 4 * H_ + h;
            #pragma unroll
            for (int r = 0; r < 4; ++r)
                dst[(size_t)r * H_] = acc[r] + comb[r * H_ + h] + b1v;
        }

    } else {                             // ---- qpre blocks ----
        const int b = bid - (S2B + PXB);
        const int h = t & 255;
        const int kh = __builtin_amdgcn_readfirstlane(t >> 8);
        float* comb = &lds[4096];

        if (t < 128) {                   // stage q row (2 KB)
            const float* Asrc = q + (size_t)b * DQ_;
            *(float4*)&lds[t * 4] = *(const float4*)(Asrc + t * 4);
        }
        __syncthreads();

        const float* wq = score_w1 + (size_t)(DS_ + DX_ + kh * 256) * H_ + h;
        const int qb = kh * 256;
        float a0 = 0.f, a1 = 0.f, a2 = 0.f, a3 = 0.f;
        #pragma unroll 4
        for (int d = 0; d < 256; d += 4) {
            const float4 q4 = *(const float4*)&lds[qb + d];
            a0 = fmaf(q4.x, wq[(size_t)(d + 0) * H_], a0);
            a1 = fmaf(q4.y, wq[(size_t)(d + 1) * H_], a1);
            a2 = fmaf(q4.z, wq[(size_t)(d + 2) * H_], a2);
            a3 = fmaf(q4.w, wq[(size_t)(d + 3) * H_], a3);
        }
        const float s = (a0 + a1) + (a2 + a3);
        if (kh) comb[h] = s;
        __syncthreads();
        if (!kh) qpre[(size_t)b * H_ + h] = s + comb[h];
    }
}

// ---------------------------------------------------------------------------
// kern3 (grid 1152 = one block per (b,k), 256 threads): logits+softmax+agg.
// (unchanged -- verified correct rounds 4-9)
// ---------------------------------------------------------------------------
__global__ __launch_bounds__(256) void kern3(
    const float* __restrict__ pre_s,     // (2048,256)
    const float* __restrict__ px,        // (1152,256)
    const float* __restrict__ qpre,      // (32,256)
    const float* __restrict__ score_w2,  // (256,1)
    const float* __restrict__ hs,        // (2048,128)
    const float* __restrict__ h_b2,      // (128)
    const float* __restrict__ x0,        // (1152,128)
    float* __restrict__ out)             // (1152,256)
{
    __shared__ float logit[M_];
    __shared__ float att[M_];
    __shared__ float pr[DX_];

    const int t    = threadIdx.x;
    const int bk   = blockIdx.x;
    const int b    = bk / K_;
    const int lane = t & 63, wave = t >> 6;
    const int hq   = lane << 2;          // h-quad base: 4 h's per lane

    float4 c4, v4;
    {
        const float4 qv = *(const float4*)(qpre + (size_t)b * H_ + hq);
        const float4 pv = *(const float4*)(px + (size_t)bk * H_ + hq);
        c4.x = qv.x + pv.x; c4.y = qv.y + pv.y;
        c4.z = qv.z + pv.z; c4.w = qv.w + pv.w;
        v4 = *(const float4*)(score_w2 + hq);
    }

    const float* ps = pre_s + (size_t)b * M_ * H_;
    #pragma unroll 4
    for (int mi = 0; mi < 16; ++mi) {
        const int m = wave * 16 + mi;
        const float4 p = *(const float4*)(ps + (size_t)m * H_ + hq);
        float x = fmaxf(p.x + c4.x, 0.f) * v4.x
                + fmaxf(p.y + c4.y, 0.f) * v4.y
                + fmaxf(p.z + c4.z, 0.f) * v4.z
                + fmaxf(p.w + c4.w, 0.f) * v4.w;
        #pragma unroll
        for (int off = 32; off > 0; off >>= 1)
            x += __shfl_xor(x, off, 64);
        if (lane == 0) logit[m] = x;
    }
    __syncthreads();

    if (wave == 0) {
        const float L = logit[lane];
        float mx = L;
        #pragma unroll
        for (int off = 32; off > 0; off >>= 1)
            mx = fmaxf(mx, __shfl_xor(mx, off, 64));
        const float e = expf(L - mx);
        float sm = e;
        #pragma unroll
        for (int off = 32; off > 0; off >>= 1)
            sm += __shfl_xor(sm, off, 64);
        att[lane] = e / sm;
    }
    __syncthreads();

    const int f = t & 127, mh = t >> 7;
    {
        const float* hsp = hs + ((size_t)b * M_ + mh * 32) * DX_ + f;
        float r = 0.f;
        #pragma unroll 4
        for (int m2 = 0; m2 < 32; ++m2)
            r = fmaf(att[mh * 32 + m2], hsp[(size_t)m2 * DX_], r);
        if (mh) pr[f] = r;
        __syncthreads();
        if (!mh)
            out[(size_t)bk * (2 * DX_) + DX_ + f] = r + pr[f] + h_b2[f];
    }
    if (t < DX_)
        out[(size_t)bk * (2 * DX_) + t] = x0[(size_t)bk * DX_ + t];
}

extern "C" void kernel_launch(void* const* d_in, const int* in_sizes, int n_in,
                              void* d_out, int out_size, void* d_ws, size_t ws_size,
                              hipStream_t stream) {
    (void)in_sizes; (void)n_in; (void)out_size; (void)ws_size;
    const float* s2       = (const float*)d_in[0];
    const float* x0       = (const float*)d_in[1];
    const float* q        = (const float*)d_in[2];
    const float* score_w1 = (const float*)d_in[3];
    const float* score_b1 = (const float*)d_in[4];
    const float* score_w2 = (const float*)d_in[5];
    // d_in[6] = score_b2 (cancels in softmax)
    const float* h_w1     = (const float*)d_in[7];
    const float* h_b1     = (const float*)d_in[8];
    const float* h_w2     = (const float*)d_in[9];
    const float* h_b2     = (const float*)d_in[10];
    float* out = (float*)d_out;

    float* ws    = (float*)d_ws;
    float* pre_s = ws;                                   // 2048*256
    float* px    = pre_s + (size_t)B_ * M_ * H_;         // 1152*256
    float* qpre  = px    + (size_t)B_ * K_ * H_;         // 32*256
    float* hs    = qpre  + (size_t)B_ * H_;              // 2048*128

    kern1<<<S2B + PXB + QPB, 512, 0, stream>>>(
        s2, x0, q, score_w1, score_b1, h_w1, h_b1, h_w2,
        pre_s, px, qpre, hs);
    kern3<<<B_ * K_, 256, 0, stream>>>(pre_s, px, qpre, score_w2, hs, h_b2,
                                       x0, out);
}

// Round 11
// 127.186 us; speedup vs baseline: 1.0658x; 1.0658x over previous
//
#include <hip/hip_runtime.h>

// Problem constants
#define B_  32
#define M_  64
#define K_  36
#define DS_ 512
#define DX_ 128
#define DQ_ 512
#define H_  256

// kern1 grid layout (round-4 best-measured config)
#define S2B 1024            // 512 tiles (4 rows) x 2 mats, in-block split-K=2
#define PXB 288             // 1152/4 rows
#define QPB 32

// ---------------------------------------------------------------------------
// kern1 (grid 1344 x 512 threads): all GEMMs, in-block split-K=2.
// Waves 0-3 (kh=0) and 4-7 (kh=1) each take half of K; one LDS combine +
// single barrier. A via block-uniform s_load_dwordx4, W per-lane scalar.
// EXACT round-4 form -- best measured (<41.8us, total 128.5).
// ---------------------------------------------------------------------------
__global__ __launch_bounds__(512, 6) void kern1(
    const float* __restrict__ s2,        // (2048,512)
    const float* __restrict__ x0,        // (1152,128)
    const float* __restrict__ q,         // (32,512)
    const float* __restrict__ score_w1,  // (1152,256)
    const float* __restrict__ score_b1,  // (256)
    const float* __restrict__ h_w1,      // (512,256)
    const float* __restrict__ h_b1,      // (256)
    float* __restrict__ pre_s,           // (2048,256)
    float* __restrict__ h1r,             // (2048,256) relu(h1+b1)
    float* __restrict__ px,              // (1152,256)
    float* __restrict__ qpre)            // (32,256)
{
    __shared__ float comb[4 * H_];       // 4 KB split-K combine buffer
    const int t   = threadIdx.x;
    const int bid = blockIdx.x;
    const int h   = t & 255;
    const int kh  = __builtin_amdgcn_readfirstlane(t >> 8);   // wave-uniform

    if (bid < S2B) {                     // ---- s2 GEMMs ----
        const int tile = bid >> 1, mat = bid & 1;
        const float* W  = mat ? h_w1 : score_w1;              // (512,256)
        const float* A  = s2 + (size_t)tile * 4 * DS_ + kh * 256;  // uniform
        const float* Wp = W + (size_t)(kh * 256) * H_ + h;

        float acc[4];
        #pragma unroll
        for (int r = 0; r < 4; ++r) acc[r] = 0.f;

        #pragma unroll 2
        for (int k = 0; k < 256; k += 4) {
            const float b0 = Wp[(size_t)(k + 0) * H_];
            const float b1 = Wp[(size_t)(k + 1) * H_];
            const float b2 = Wp[(size_t)(k + 2) * H_];
            const float b3 = Wp[(size_t)(k + 3) * H_];
            #pragma unroll
            for (int r = 0; r < 4; ++r) {
                const float4 a = *(const float4*)(A + (size_t)r * DS_ + k);
                acc[r] = fmaf(a.x, b0, acc[r]);
                acc[r] = fmaf(a.y, b1, acc[r]);
                acc[r] = fmaf(a.z, b2, acc[r]);
                acc[r] = fmaf(a.w, b3, acc[r]);
            }
        }
        if (kh) {
            #pragma unroll
            for (int r = 0; r < 4; ++r) comb[r * H_ + h] = acc[r];
        }
        __syncthreads();
        if (!kh) {
            if (!mat) {
                float* dst = pre_s + (size_t)tile * 4 * H_ + h;
                #pragma unroll
                for (int r = 0; r < 4; ++r)
                    dst[(size_t)r * H_] = acc[r] + comb[r * H_ + h];
            } else {
                const float b1v = h_b1[h];
                float* dst = h1r + (size_t)tile * 4 * H_ + h;
                #pragma unroll
                for (int r = 0; r < 4; ++r)
                    dst[(size_t)r * H_] =
                        fmaxf(acc[r] + comb[r * H_ + h] + b1v, 0.f);
            }
        }

    } else if (bid < S2B + PXB) {        // ---- px blocks (K=128) ----
        const int tile = bid - S2B;
        const float* A  = x0 + (size_t)tile * 4 * DX_ + kh * 64;   // uniform
        const float* Wp = score_w1 + (size_t)(DS_ + kh * 64) * H_ + h;

        float acc[4];
        #pragma unroll
        for (int r = 0; r < 4; ++r) acc[r] = 0.f;

        #pragma unroll 2
        for (int k = 0; k < 64; k += 4) {
            const float b0 = Wp[(size_t)(k + 0) * H_];
            const float b1 = Wp[(size_t)(k + 1) * H_];
            const float b2 = Wp[(size_t)(k + 2) * H_];
            const float b3 = Wp[(size_t)(k + 3) * H_];
            #pragma unroll
            for (int r = 0; r < 4; ++r) {
                const float4 a = *(const float4*)(A + (size_t)r * DX_ + k);
                acc[r] = fmaf(a.x, b0, acc[r]);
                acc[r] = fmaf(a.y, b1, acc[r]);
                acc[r] = fmaf(a.z, b2, acc[r]);
                acc[r] = fmaf(a.w, b3, acc[r]);
            }
        }
        if (kh) {
            #pragma unroll
            for (int r = 0; r < 4; ++r) comb[r * H_ + h] = acc[r];
        }
        __syncthreads();
        if (!kh) {
            const float b1v = score_b1[h];
            float* dst = px + (size_t)tile * 4 * H_ + h;
            #pragma unroll
            for (int r = 0; r < 4; ++r)
                dst[(size_t)r * H_] = acc[r] + comb[r * H_ + h] + b1v;
        }

    } else {                             // ---- qpre blocks ----
        const int b = bid - (S2B + PXB);
        const float* qp = q + (size_t)b * DQ_ + kh * 256;          // uniform
        const float* wq = score_w1 + (size_t)(DS_ + DX_ + kh * 256) * H_ + h;
        float a0 = 0.f, a1 = 0.f, a2 = 0.f, a3 = 0.f;
        #pragma unroll 2
        for (int d = 0; d < 256; d += 4) {
            const float4 q4 = *(const float4*)(qp + d);
            a0 = fmaf(q4.x, wq[(size_t)(d + 0) * H_], a0);
            a1 = fmaf(q4.y, wq[(size_t)(d + 1) * H_], a1);
            a2 = fmaf(q4.z, wq[(size_t)(d + 2) * H_], a2);
            a3 = fmaf(q4.w, wq[(size_t)(d + 3) * H_], a3);
        }
        const float s = (a0 + a1) + (a2 + a3);
        if (kh) comb[h] = s;
        __syncthreads();
        if (!kh) qpre[(size_t)b * H_ + h] = s + comb[h];
    }
}

// ---------------------------------------------------------------------------
// kern2 (grid 512 x 256): hs = h1r @ h_w2  (exact round-4 form)
// 4 rows/block, split-K=2 across thread groups, float4 w2 loads.
// ---------------------------------------------------------------------------
__global__ __launch_bounds__(256) void kern2(
    const float* __restrict__ h1r,       // (2048,256) already relu'd
    const float* __restrict__ h_w2,      // (256,128)
    float* __restrict__ hs)              // (2048,128)
{
    __shared__ float A[4 * H_];
    __shared__ float part[4][DX_];
    const int t  = threadIdx.x;
    const int r0 = blockIdx.x * 4;

    {
        const int flat = t * 4;
        *(float4*)&A[flat] = *(const float4*)(h1r + (size_t)r0 * H_ + flat);
    }
    __syncthreads();

    const int fq  = (t & 31) * 4;
    const int g   = t >> 5;
    const int row = g & 3, kh = g >> 2;
    const float* ap = &A[row * H_ + kh * 128];
    const float* wp = h_w2 + (size_t)(kh * 128) * DX_ + fq;

    float4 acc = {0.f, 0.f, 0.f, 0.f};
    #pragma unroll 4
    for (int d = 0; d < 128; d += 4) {
        const float a0 = ap[d], a1 = ap[d + 1], a2 = ap[d + 2], a3 = ap[d + 3];
        const float4 w0  = *(const float4*)(wp + (size_t)(d + 0) * DX_);
        const float4 w1  = *(const float4*)(wp + (size_t)(d + 1) * DX_);
        const float4 w2v = *(const float4*)(wp + (size_t)(d + 2) * DX_);
        const float4 w3  = *(const float4*)(wp + (size_t)(d + 3) * DX_);
        acc.x = fmaf(a0, w0.x, acc.x); acc.y = fmaf(a0, w0.y, acc.y);
        acc.z = fmaf(a0, w0.z, acc.z); acc.w = fmaf(a0, w0.w, acc.w);
        acc.x = fmaf(a1, w1.x, acc.x); acc.y = fmaf(a1, w1.y, acc.y);
        acc.z = fmaf(a1, w1.z, acc.z); acc.w = fmaf(a1, w1.w, acc.w);
        acc.x = fmaf(a2, w2v.x, acc.x); acc.y = fmaf(a2, w2v.y, acc.y);
        acc.z = fmaf(a2, w2v.z, acc.z); acc.w = fmaf(a2, w2v.w, acc.w);
        acc.x = fmaf(a3, w3.x, acc.x); acc.y = fmaf(a3, w3.y, acc.y);
        acc.z = fmaf(a3, w3.z, acc.z); acc.w = fmaf(a3, w3.w, acc.w);
    }
    if (kh) *(float4*)&part[row][fq] = acc;
    __syncthreads();
    if (!kh) {
        const float4 p = *(const float4*)&part[row][fq];
        float4 o;
        o.x = acc.x + p.x; o.y = acc.y + p.y;
        o.z = acc.z + p.z; o.w = acc.w + p.w;
        *(float4*)(hs + (size_t)(r0 + row) * DX_ + fq) = o;
    }
}

// ---------------------------------------------------------------------------
// kern3 (grid 1152, 256 threads): logits+softmax+agg.
// Round-4 form + ONE edit: the 32 hs loads per thread are hoisted into
// registers (hv[32], fully unrolled -> static indices) BEFORE the logit
// phase, so their L2 latency overlaps logits+softmax instead of sitting
// serial behind them.
// ---------------------------------------------------------------------------
__global__ __launch_bounds__(256) void kern3(
    const float* __restrict__ pre_s,     // (2048,256)
    const float* __restrict__ px,        // (1152,256)
    const float* __restrict__ qpre,      // (32,256)
    const float* __restrict__ score_w2,  // (256,1)
    const float* __restrict__ hs,        // (2048,128)
    const float* __restrict__ h_b2,      // (128)
    const float* __restrict__ x0,        // (1152,128)
    float* __restrict__ out)             // (1152,256)
{
    __shared__ float logit[M_];
    __shared__ float att[M_];
    __shared__ float pr[DX_];

    const int t    = threadIdx.x;
    const int bk   = blockIdx.x;
    const int b    = bk / K_;
    const int lane = t & 63, wave = t >> 6;
    const int hq   = lane << 2;          // h-quad base: 4 h's per lane
    const int f    = t & 127, mh = t >> 7;

    float4 c4, v4;
    {
        const float4 qv = *(const float4*)(qpre + (size_t)b * H_ + hq);
        const float4 pv = *(const float4*)(px + (size_t)bk * H_ + hq);
        c4.x = qv.x + pv.x; c4.y = qv.y + pv.y;
        c4.z = qv.z + pv.z; c4.w = qv.w + pv.w;
        v4 = *(const float4*)(score_w2 + hq);
    }

    // ---- EARLY ISSUE: agg-phase hs loads into registers (latency hides
    // under the logit + softmax phases below) ----
    float hv[32];
    {
        const float* hsp = hs + ((size_t)b * M_ + mh * 32) * DX_ + f;
        #pragma unroll
        for (int m2 = 0; m2 < 32; ++m2)
            hv[m2] = hsp[(size_t)m2 * DX_];
    }

    // ---- logits: wave handles m = wave*16 .. +15 ----
    const float* ps = pre_s + (size_t)b * M_ * H_;
    #pragma unroll 2
    for (int mi = 0; mi < 16; ++mi) {
        const int m = wave * 16 + mi;
        const float4 p = *(const float4*)(ps + (size_t)m * H_ + hq);
        float x = fmaxf(p.x + c4.x, 0.f) * v4.x
                + fmaxf(p.y + c4.y, 0.f) * v4.y
                + fmaxf(p.z + c4.z, 0.f) * v4.z
                + fmaxf(p.w + c4.w, 0.f) * v4.w;
        #pragma unroll
        for (int off = 32; off > 0; off >>= 1)
            x += __shfl_xor(x, off, 64);
        if (lane == 0) logit[m] = x;
    }
    __syncthreads();

    // ---- softmax over m (wave 0, lane = m) ----
    if (wave == 0) {
        const float L = logit[lane];
        float mx = L;
        #pragma unroll
        for (int off = 32; off > 0; off >>= 1)
            mx = fmaxf(mx, __shfl_xor(mx, off, 64));
        const float e = expf(L - mx);
        float sm = e;
        #pragma unroll
        for (int off = 32; off > 0; off >>= 1)
            sm += __shfl_xor(sm, off, 64);
        att[lane] = e / sm;
    }
    __syncthreads();

    // ---- agg: out[bk,128+f] = sum_m att[m]*hv[m] + h_b2[f] ----
    {
        float r = 0.f;
        #pragma unroll
        for (int m2 = 0; m2 < 32; ++m2)
            r = fmaf(att[mh * 32 + m2], hv[m2], r);
        if (mh) pr[f] = r;
        __syncthreads();
        if (!mh)
            out[(size_t)bk * (2 * DX_) + DX_ + f] = r + pr[f] + h_b2[f];
    }
    // ---- passthrough out[:,0:128] = x0 ----
    if (t < DX_)
        out[(size_t)bk * (2 * DX_) + t] = x0[(size_t)bk * DX_ + t];
}

extern "C" void kernel_launch(void* const* d_in, const int* in_sizes, int n_in,
                              void* d_out, int out_size, void* d_ws, size_t ws_size,
                              hipStream_t stream) {
    (void)in_sizes; (void)n_in; (void)out_size; (void)ws_size;
    const float* s2       = (const float*)d_in[0];
    const float* x0       = (const float*)d_in[1];
    const float* q        = (const float*)d_in[2];
    const float* score_w1 = (const float*)d_in[3];
    const float* score_b1 = (const float*)d_in[4];
    const float* score_w2 = (const float*)d_in[5];
    // d_in[6] = score_b2 (cancels in softmax)
    const float* h_w1     = (const float*)d_in[7];
    const float* h_b1     = (const float*)d_in[8];
    const float* h_w2     = (const float*)d_in[9];
    const float* h_b2     = (const float*)d_in[10];
    float* out = (float*)d_out;

    float* ws    = (float*)d_ws;
    float* pre_s = ws;                                   // 2048*256
    float* h1r   = pre_s + (size_t)B_ * M_ * H_;         // 2048*256
    float* px    = h1r   + (size_t)B_ * M_ * H_;         // 1152*256
    float* qpre  = px    + (size_t)B_ * K_ * H_;         // 32*256
    float* hs    = qpre  + (size_t)B_ * H_;              // 2048*128

    kern1<<<S2B + PXB + QPB, 512, 0, stream>>>(
        s2, x0, q, score_w1, score_b1, h_w1, h_b1, pre_s, h1r, px, qpre);
    kern2<<<512, 256, 0, stream>>>(h1r, h_w2, hs);
    kern3<<<B_ * K_, 256, 0, stream>>>(pre_s, px, qpre, score_w2, hs, h_b2,
                                       x0, out);
}

// Round 12
// 117.932 us; speedup vs baseline: 1.1495x; 1.0785x over previous
//
#include <hip/hip_runtime.h>

// Problem constants
#define B_  32
#define M_  64
#define K_  36
#define DS_ 512
#define DX_ 128
#define DQ_ 512
#define H_  256

typedef __attribute__((ext_vector_type(8))) short short8v;
typedef __attribute__((ext_vector_type(4))) float float4v;

// kernP grid layout
#define PK_S2 128           // s2 pack: one block per 16-row tile
#define PK_W  32            // W pack: (mat,nt) pairs
#define PXB   288           // px: 1152/4 rows  (round-11 form)
#define QPB   32            // qpre

// ---------------------------------------------------------------------------
// kernP (grid 480 x 512): operand packing for MFMA + px + qpre.
//  blocks [0,128):   pack s2 tile rt (16 rows x 512 k) into bf16 hi/lo
//                    fragments Apk[rt][ks][lane][8], fragment layout
//                    row=l&15, k=ks*32+((l>>4)<<2)+(i&3)+((i>>2)<<4).
//  blocks [128,160): pack W (mat=wi>>4: 0=w_s,1=h_w1; nt=wi&15) into
//                    Bpk[wi][ks][lane][8]: col=nt*16+(l&15), same k pattern.
//  blocks [160,448): px[4 rows] = x0@w_x + score_b1   (round-11 VALU form)
//  blocks [448,480): qpre[b]    = q[b]@w_q            (round-11 VALU form)
// hi = bf16-truncate(a); lo = bf16-truncate(a - hi)  (residual capture).
// ---------------------------------------------------------------------------
__global__ __launch_bounds__(512) void kernP(
    const float* __restrict__ s2,        // (2048,512)
    const float* __restrict__ x0,        // (1152,128)
    const float* __restrict__ q,         // (32,512)
    const float* __restrict__ score_w1,  // (1152,256)
    const float* __restrict__ score_b1,  // (256)
    const float* __restrict__ h_w1,      // (512,256)
    unsigned short* __restrict__ Apk_h,  // 128*16*64*8
    unsigned short* __restrict__ Apk_l,
    unsigned short* __restrict__ Bpk_h,  // 32*16*64*8
    unsigned short* __restrict__ Bpk_l,
    float* __restrict__ px,              // (1152,256)
    float* __restrict__ qpre)            // (32,256)
{
    __shared__ float comb[4 * H_];
    const int t   = threadIdx.x;
    const int bid = blockIdx.x;

    if (bid < PK_S2) {                   // ---- pack s2 ----
        const int rt = bid;
        const float* src = s2 + (size_t)rt * 16 * DS_;
        unsigned short* dh = Apk_h + (size_t)rt * 8192;
        unsigned short* dl = Apk_l + (size_t)rt * 8192;
        #pragma unroll 4
        for (int j = 0; j < 16; ++j) {
            const int f  = t * 16 + j;           // 0..8191
            const int i  = f & 7;
            const int l  = (f >> 3) & 63;
            const int ks = f >> 9;
            const int row = l & 15;
            const int k  = ks * 32 + ((l >> 4) << 2) + (i & 3) + ((i >> 2) << 4);
            const float a = src[(size_t)row * DS_ + k];
            const unsigned u  = __float_as_uint(a);
            const unsigned short hi = (unsigned short)(u >> 16);
            const float res = a - __uint_as_float((unsigned)hi << 16);
            const unsigned short lo =
                (unsigned short)(__float_as_uint(res) >> 16);
            dh[f] = hi; dl[f] = lo;
        }

    } else if (bid < PK_S2 + PK_W) {     // ---- pack W ----
        const int wi  = bid - PK_S2;     // mat*16 + nt
        const int mat = wi >> 4, nt = wi & 15;
        const float* Wsrc = mat ? h_w1 : score_w1;   // (512,256)
        unsigned short* dh = Bpk_h + (size_t)wi * 8192;
        unsigned short* dl = Bpk_l + (size_t)wi * 8192;
        #pragma unroll 4
        for (int j = 0; j < 16; ++j) {
            const int f  = t * 16 + j;
            const int i  = f & 7;
            const int l  = (f >> 3) & 63;
            const int ks = f >> 9;
            const int col = nt * 16 + (l & 15);
            const int k  = ks * 32 + ((l >> 4) << 2) + (i & 3) + ((i >> 2) << 4);
            const float a = Wsrc[(size_t)k * H_ + col];
            const unsigned u  = __float_as_uint(a);
            const unsigned short hi = (unsigned short)(u >> 16);
            const float res = a - __uint_as_float((unsigned)hi << 16);
            const unsigned short lo =
                (unsigned short)(__float_as_uint(res) >> 16);
            dh[f] = hi; dl[f] = lo;
        }

    } else if (bid < PK_S2 + PK_W + PXB) {   // ---- px blocks (K=128) ----
        const int tile = bid - (PK_S2 + PK_W);
        const int h    = t & 255;
        const int kh   = __builtin_amdgcn_readfirstlane(t >> 8);
        const float* A  = x0 + (size_t)tile * 4 * DX_ + kh * 64;   // uniform
        const float* Wp = score_w1 + (size_t)(DS_ + kh * 64) * H_ + h;

        float acc[4];
        #pragma unroll
        for (int r = 0; r < 4; ++r) acc[r] = 0.f;

        #pragma unroll 2
        for (int k = 0; k < 64; k += 4) {
            const float b0 = Wp[(size_t)(k + 0) * H_];
            const float b1 = Wp[(size_t)(k + 1) * H_];
            const float b2 = Wp[(size_t)(k + 2) * H_];
            const float b3 = Wp[(size_t)(k + 3) * H_];
            #pragma unroll
            for (int r = 0; r < 4; ++r) {
                const float4 a = *(const float4*)(A + (size_t)r * DX_ + k);
                acc[r] = fmaf(a.x, b0, acc[r]);
                acc[r] = fmaf(a.y, b1, acc[r]);
                acc[r] = fmaf(a.z, b2, acc[r]);
                acc[r] = fmaf(a.w, b3, acc[r]);
            }
        }
        if (kh) {
            #pragma unroll
            for (int r = 0; r < 4; ++r) comb[r * H_ + h] = acc[r];
        }
        __syncthreads();
        if (!kh) {
            const float b1v = score_b1[h];
            float* dst = px + (size_t)tile * 4 * H_ + h;
            #pragma unroll
            for (int r = 0; r < 4; ++r)
                dst[(size_t)r * H_] = acc[r] + comb[r * H_ + h] + b1v;
        }

    } else {                             // ---- qpre blocks ----
        const int b  = bid - (PK_S2 + PK_W + PXB);
        const int h  = t & 255;
        const int kh = __builtin_amdgcn_readfirstlane(t >> 8);
        const float* qp = q + (size_t)b * DQ_ + kh * 256;          // uniform
        const float* wq = score_w1 + (size_t)(DS_ + DX_ + kh * 256) * H_ + h;
        float a0 = 0.f, a1 = 0.f, a2 = 0.f, a3 = 0.f;
        #pragma unroll 2
        for (int d = 0; d < 256; d += 4) {
            const float4 q4 = *(const float4*)(qp + d);
            a0 = fmaf(q4.x, wq[(size_t)(d + 0) * H_], a0);
            a1 = fmaf(q4.y, wq[(size_t)(d + 1) * H_], a1);
            a2 = fmaf(q4.z, wq[(size_t)(d + 2) * H_], a2);
            a3 = fmaf(q4.w, wq[(size_t)(d + 3) * H_], a3);
        }
        const float s = (a0 + a1) + (a2 + a3);
        if (kh) comb[h] = s;
        __syncthreads();
        if (!kh) qpre[(size_t)b * H_ + h] = s + comb[h];
    }
}

// ---------------------------------------------------------------------------
// kernG (grid 2048 x 64): MFMA s2-GEMMs via bf16 hi/lo split.
// bid = rt*16 + mat*8 + ns. Wave computes a 16x32 output tile:
// nt = ns*2, ns*2+1. Per k-step (K=32): 6 coalesced dwordx4 fragment loads
// + 9 MFMAs into 6 INDEPENDENT accumulator chains (hh, hl, lh per nt).
// a*w = ah*wh + ah*wl + al*wh  (al*wl ~ 2^-18, dropped).
//   mat=0: pre_s = s2@w_s
//   mat=1: h1r  = relu(s2@h_w1 + h_b1)   (bias+relu fused in epilogue)
// C/D layout: col = l&15, row = (l>>4)*4 + r   [m89-verified].
// ---------------------------------------------------------------------------
__global__ __launch_bounds__(64) void kernG(
    const unsigned short* __restrict__ Apk_h,
    const unsigned short* __restrict__ Apk_l,
    const unsigned short* __restrict__ Bpk_h,
    const unsigned short* __restrict__ Bpk_l,
    const float* __restrict__ h_b1,      // (256)
    float* __restrict__ pre_s,           // (2048,256)
    float* __restrict__ h1r)             // (2048,256) relu(h1+b1)
{
    const int l   = threadIdx.x;
    const int bid = blockIdx.x;
    const int ns  = bid & 7;
    const int mat = (bid >> 3) & 1;
    const int rt  = bid >> 4;

    const short8v* Ah = (const short8v*)Apk_h + (size_t)rt * 16 * 64 + l;
    const short8v* Al = (const short8v*)Apk_l + (size_t)rt * 16 * 64 + l;
    const int nt0 = mat * 16 + ns * 2;
    const short8v* B0h = (const short8v*)Bpk_h + (size_t)nt0 * 16 * 64 + l;
    const short8v* B0l = (const short8v*)Bpk_l + (size_t)nt0 * 16 * 64 + l;
    const short8v* B1h = B0h + 16 * 64;
    const short8v* B1l = B0l + 16 * 64;

    float4v aA0 = {0.f, 0.f, 0.f, 0.f}, aB0 = aA0, aC0 = aA0;
    float4v aA1 = aA0, aB1 = aA0, aC1 = aA0;

    #pragma unroll 2
    for (int ks = 0; ks < 16; ++ks) {
        const short8v ah  = Ah[(size_t)ks * 64];
        const short8v al  = Al[(size_t)ks * 64];
        const short8v b0h = B0h[(size_t)ks * 64];
        const short8v b0l = B0l[(size_t)ks * 64];
        const short8v b1h = B1h[(size_t)ks * 64];
        const short8v b1l = B1l[(size_t)ks * 64];
        aA0 = __builtin_amdgcn_mfma_f32_16x16x32_bf16(ah, b0h, aA0, 0, 0, 0);
        aB0 = __builtin_amdgcn_mfma_f32_16x16x32_bf16(ah, b0l, aB0, 0, 0, 0);
        aC0 = __builtin_amdgcn_mfma_f32_16x16x32_bf16(al, b0h, aC0, 0, 0, 0);
        aA1 = __builtin_amdgcn_mfma_f32_16x16x32_bf16(ah, b1h, aA1, 0, 0, 0);
        aB1 = __builtin_amdgcn_mfma_f32_16x16x32_bf16(ah, b1l, aB1, 0, 0, 0);
        aC1 = __builtin_amdgcn_mfma_f32_16x16x32_bf16(al, b1h, aC1, 0, 0, 0);
    }

    const float4v s0 = aA0 + aB0 + aC0;
    const float4v s1 = aA1 + aB1 + aC1;

    const int row0 = rt * 16 + ((l >> 4) << 2);
    const int c0   = ns * 32 + (l & 15);

    if (!mat) {
        #pragma unroll
        for (int r = 0; r < 4; ++r) {
            pre_s[(size_t)(row0 + r) * H_ + c0]      = s0[r];
            pre_s[(size_t)(row0 + r) * H_ + c0 + 16] = s1[r];
        }
    } else {
        const float bv0 = h_b1[c0];
        const float bv1 = h_b1[c0 + 16];
        #pragma unroll
        for (int r = 0; r < 4; ++r) {
            h1r[(size_t)(row0 + r) * H_ + c0]      = fmaxf(s0[r] + bv0, 0.f);
            h1r[(size_t)(row0 + r) * H_ + c0 + 16] = fmaxf(s1[r] + bv1, 0.f);
        }
    }
}

// ---------------------------------------------------------------------------
// kern2 (grid 512 x 256): hs = h1r @ h_w2  (round-11 verified form)
// ---------------------------------------------------------------------------
__global__ __launch_bounds__(256) void kern2(
    const float* __restrict__ h1r,       // (2048,256) already relu'd
    const float* __restrict__ h_w2,      // (256,128)
    float* __restrict__ hs)              // (2048,128)
{
    __shared__ float A[4 * H_];
    __shared__ float part[4][DX_];
    const int t  = threadIdx.x;
    const int r0 = blockIdx.x * 4;

    {
        const int flat = t * 4;
        *(float4*)&A[flat] = *(const float4*)(h1r + (size_t)r0 * H_ + flat);
    }
    __syncthreads();

    const int fq  = (t & 31) * 4;
    const int g   = t >> 5;
    const int row = g & 3, kh = g >> 2;
    const float* ap = &A[row * H_ + kh * 128];
    const float* wp = h_w2 + (size_t)(kh * 128) * DX_ + fq;

    float4 acc = {0.f, 0.f, 0.f, 0.f};
    #pragma unroll 4
    for (int d = 0; d < 128; d += 4) {
        const float a0 = ap[d], a1 = ap[d + 1], a2 = ap[d + 2], a3 = ap[d + 3];
        const float4 w0  = *(const float4*)(wp + (size_t)(d + 0) * DX_);
        const float4 w1  = *(const float4*)(wp + (size_t)(d + 1) * DX_);
        const float4 w2v = *(const float4*)(wp + (size_t)(d + 2) * DX_);
        const float4 w3  = *(const float4*)(wp + (size_t)(d + 3) * DX_);
        acc.x = fmaf(a0, w0.x, acc.x); acc.y = fmaf(a0, w0.y, acc.y);
        acc.z = fmaf(a0, w0.z, acc.z); acc.w = fmaf(a0, w0.w, acc.w);
        acc.x = fmaf(a1, w1.x, acc.x); acc.y = fmaf(a1, w1.y, acc.y);
        acc.z = fmaf(a1, w1.z, acc.z); acc.w = fmaf(a1, w1.w, acc.w);
        acc.x = fmaf(a2, w2v.x, acc.x); acc.y = fmaf(a2, w2v.y, acc.y);
        acc.z = fmaf(a2, w2v.z, acc.z); acc.w = fmaf(a2, w2v.w, acc.w);
        acc.x = fmaf(a3, w3.x, acc.x); acc.y = fmaf(a3, w3.y, acc.y);
        acc.z = fmaf(a3, w3.z, acc.z); acc.w = fmaf(a3, w3.w, acc.w);
    }
    if (kh) *(float4*)&part[row][fq] = acc;
    __syncthreads();
    if (!kh) {
        const float4 p = *(const float4*)&part[row][fq];
        float4 o;
        o.x = acc.x + p.x; o.y = acc.y + p.y;
        o.z = acc.z + p.z; o.w = acc.w + p.w;
        *(float4*)(hs + (size_t)(r0 + row) * DX_ + fq) = o;
    }
}

// ---------------------------------------------------------------------------
// kern3 (grid 1152, 256 threads): logits+softmax+agg. (round-11 verified
// form with early hs register hoist)
// ---------------------------------------------------------------------------
__global__ __launch_bounds__(256) void kern3(
    const float* __restrict__ pre_s,     // (2048,256)
    const float* __restrict__ px,        // (1152,256)
    const float* __restrict__ qpre,      // (32,256)
    const float* __restrict__ score_w2,  // (256,1)
    const float* __restrict__ hs,        // (2048,128)
    const float* __restrict__ h_b2,      // (128)
    const float* __restrict__ x0,        // (1152,128)
    float* __restrict__ out)             // (1152,256)
{
    __shared__ float logit[M_];
    __shared__ float att[M_];
    __shared__ float pr[DX_];

    const int t    = threadIdx.x;
    const int bk   = blockIdx.x;
    const int b    = bk / K_;
    const int lane = t & 63, wave = t >> 6;
    const int hq   = lane << 2;
    const int f    = t & 127, mh = t >> 7;

    float4 c4, v4;
    {
        const float4 qv = *(const float4*)(qpre + (size_t)b * H_ + hq);
        const float4 pv = *(const float4*)(px + (size_t)bk * H_ + hq);
        c4.x = qv.x + pv.x; c4.y = qv.y + pv.y;
        c4.z = qv.z + pv.z; c4.w = qv.w + pv.w;
        v4 = *(const float4*)(score_w2 + hq);
    }

    float hv[32];
    {
        const float* hsp = hs + ((size_t)b * M_ + mh * 32) * DX_ + f;
        #pragma unroll
        for (int m2 = 0; m2 < 32; ++m2)
            hv[m2] = hsp[(size_t)m2 * DX_];
    }

    const float* ps = pre_s + (size_t)b * M_ * H_;
    #pragma unroll 2
    for (int mi = 0; mi < 16; ++mi) {
        const int m = wave * 16 + mi;
        const float4 p = *(const float4*)(ps + (size_t)m * H_ + hq);
        float x = fmaxf(p.x + c4.x, 0.f) * v4.x
                + fmaxf(p.y + c4.y, 0.f) * v4.y
                + fmaxf(p.z + c4.z, 0.f) * v4.z
                + fmaxf(p.w + c4.w, 0.f) * v4.w;
        #pragma unroll
        for (int off = 32; off > 0; off >>= 1)
            x += __shfl_xor(x, off, 64);
        if (lane == 0) logit[m] = x;
    }
    __syncthreads();

    if (wave == 0) {
        const float L = logit[lane];
        float mx = L;
        #pragma unroll
        for (int off = 32; off > 0; off >>= 1)
            mx = fmaxf(mx, __shfl_xor(mx, off, 64));
        const float e = expf(L - mx);
        float sm = e;
        #pragma unroll
        for (int off = 32; off > 0; off >>= 1)
            sm += __shfl_xor(sm, off, 64);
        att[lane] = e / sm;
    }
    __syncthreads();

    {
        float r = 0.f;
        #pragma unroll
        for (int m2 = 0; m2 < 32; ++m2)
            r = fmaf(att[mh * 32 + m2], hv[m2], r);
        if (mh) pr[f] = r;
        __syncthreads();
        if (!mh)
            out[(size_t)bk * (2 * DX_) + DX_ + f] = r + pr[f] + h_b2[f];
    }
    if (t < DX_)
        out[(size_t)bk * (2 * DX_) + t] = x0[(size_t)bk * DX_ + t];
}

extern "C" void kernel_launch(void* const* d_in, const int* in_sizes, int n_in,
                              void* d_out, int out_size, void* d_ws, size_t ws_size,
                              hipStream_t stream) {
    (void)in_sizes; (void)n_in; (void)out_size; (void)ws_size;
    const float* s2       = (const float*)d_in[0];
    const float* x0       = (const float*)d_in[1];
    const float* q        = (const float*)d_in[2];
    const float* score_w1 = (const float*)d_in[3];
    const float* score_b1 = (const float*)d_in[4];
    const float* score_w2 = (const float*)d_in[5];
    // d_in[6] = score_b2 (cancels in softmax)
    const float* h_w1     = (const float*)d_in[7];
    const float* h_b1     = (const float*)d_in[8];
    const float* h_w2     = (const float*)d_in[9];
    const float* h_b2     = (const float*)d_in[10];
    float* out = (float*)d_out;

    float* ws    = (float*)d_ws;
    float* pre_s = ws;                                   // 2048*256
    float* h1r   = pre_s + (size_t)B_ * M_ * H_;         // 2048*256
    float* px    = h1r   + (size_t)B_ * M_ * H_;         // 1152*256
    float* qpre  = px    + (size_t)B_ * K_ * H_;         // 32*256
    float* hs    = qpre  + (size_t)B_ * H_;              // 2048*128

    // bf16 fragment packs at +8 MB (16B-aligned)
    unsigned short* Apk_h = (unsigned short*)(ws + 2097152);
    unsigned short* Apk_l = Apk_h + (size_t)128 * 16 * 64 * 8;  // +1M ushort
    unsigned short* Bpk_h = Apk_l + (size_t)128 * 16 * 64 * 8;
    unsigned short* Bpk_l = Bpk_h + (size_t)32 * 16 * 64 * 8;

    kernP<<<PK_S2 + PK_W + PXB + QPB, 512, 0, stream>>>(
        s2, x0, q, score_w1, score_b1, h_w1,
        Apk_h, Apk_l, Bpk_h, Bpk_l, px, qpre);
    kernG<<<2048, 64, 0, stream>>>(Apk_h, Apk_l, Bpk_h, Bpk_l, h_b1,
                                   pre_s, h1r);
    kern2<<<512, 256, 0, stream>>>(h1r, h_w2, hs);
    kern3<<<B_ * K_, 256, 0, stream>>>(pre_s, px, qpre, score_w2, hs, h_b2,
                                       x0, out);
}